// Round 1
// baseline (22583.678 us; speedup 1.0000x reference)
//
#include <hip/hip_runtime.h>
#include <hip/hip_bf16.h>

#define B_    256
#define S_    512
#define H_    256
#define TLEN_ 32
#define DI_   5
#define ENCSTRIDE 131072   // S_*H_

// ---------------------------------------------------------------------------
// init: zero state buffers, set decoder inp0 = ones
// ---------------------------------------------------------------------------
__global__ __launch_bounds__(256) void init_kernel(float* h1b, float* h2b, float* c1,
                                                   float* c2, float* zb, float* pred) {
    int i = blockIdx.x * 256 + threadIdx.x;      // grid 256 -> 65536
    h1b[i] = 0.f; h2b[i] = 0.f; c1[i] = 0.f; c2[i] = 0.f; zb[i] = 0.f;
    if (i < B_ * DI_) pred[i] = 1.0f;
}

// ---------------------------------------------------------------------------
// pack a [1024][256] row-major weight into [k4][n] float4 layout:
// out[k4*1024 + n] = {w[n][4k4], w[n][4k4+1], w[n][4k4+2], w[n][4k4+3]}
// ---------------------------------------------------------------------------
__global__ __launch_bounds__(256) void pack_kernel(const float* __restrict__ m,
                                                   float4* __restrict__ out) {
    int idx = blockIdx.x * 256 + threadIdx.x;    // grid 256 -> 65536
    int k4 = idx >> 10, n = idx & 1023;
    out[idx] = ((const float4*)m)[n * 64 + k4];
}

// ---------------------------------------------------------------------------
// Weff[n][m] = sum_k wih_d1[n][k]*wdi[k][m]; beff[n] = b_d1[n] + sum_k wih_d1[n][k]*bdi[k]
// ---------------------------------------------------------------------------
__global__ __launch_bounds__(256) void weff_kernel(const float* __restrict__ wih_d1,
                                                   const float* __restrict__ wdi,
                                                   const float* __restrict__ bdi,
                                                   const float* __restrict__ b_d1,
                                                   float* __restrict__ weff,
                                                   float* __restrict__ beff) {
    int n = blockIdx.x * 256 + threadIdx.x;      // grid 4 -> 1024
    float acc[DI_] = {0.f, 0.f, 0.f, 0.f, 0.f};
    float accb = 0.f;
    for (int k = 0; k < H_; k++) {
        float w = wih_d1[n * H_ + k];
        accb += w * bdi[k];
#pragma unroll
        for (int m = 0; m < DI_; m++) acc[m] += w * wdi[k * DI_ + m];
    }
#pragma unroll
    for (int m = 0; m < DI_; m++) weff[n * DI_ + m] = acc[m];
    beff[n] = b_d1[n] + accb;
}

// ---------------------------------------------------------------------------
// Generic LSTM cell step. One (b,j) cell per thread.
// gates[n] = bias[n] + x.wih[n] (+ hprev.whh[n]); pytorch order i,f,g,o.
// Tile: 8 batch rows x 32 j cols per WG; grid 256 WGs x 256 threads.
// kx==5  : wih5  [1024][5] row-major (unpacked)
// kx==256: wihp  packed [64][1024] float4
// ---------------------------------------------------------------------------
__global__ __launch_bounds__(256) void cell_kernel(
    const float* __restrict__ x, int xstride,
    const float* __restrict__ wih5,
    const float4* __restrict__ wihp,
    int kx,
    const float* __restrict__ hprev,
    const float4* __restrict__ whhp,
    int use_whh,
    const float* __restrict__ bias,
    const float* __restrict__ cprev,
    float* __restrict__ cout,
    float* __restrict__ hout,
    __hip_bfloat16* __restrict__ henc)   // pre-offset by t*H_, row stride ENCSTRIDE; or null
{
    __shared__ float lx[8][H_];
    __shared__ float lh[8][H_];
    int tid = threadIdx.x;
    int b0 = (int)(blockIdx.x >> 3) * 8;
    int j0 = (int)(blockIdx.x & 7) * 32;

    if (kx == DI_) {
        if (tid < 8 * DI_) {
            int r = tid / DI_, c = tid % DI_;
            lx[r][c] = x[(b0 + r) * xstride + c];
        }
    } else {
        for (int i = tid; i < 8 * 64; i += 256) {
            int r = i >> 6, c4 = i & 63;
            ((float4*)lx[r])[c4] = ((const float4*)(x + (long)(b0 + r) * xstride))[c4];
        }
    }
    if (use_whh) {
        for (int i = tid; i < 8 * 64; i += 256) {
            int r = i >> 6, c4 = i & 63;
            ((float4*)lh[r])[c4] = ((const float4*)(hprev + (long)(b0 + r) * H_))[c4];
        }
    }
    __syncthreads();

    int ty = tid >> 5, tx = tid & 31;
    int b = b0 + ty, j = j0 + tx;
    float a0 = bias[j], a1 = bias[256 + j], a2 = bias[512 + j], a3 = bias[768 + j];

    if (kx == DI_) {
#pragma unroll
        for (int k = 0; k < DI_; k++) {
            float xv = lx[ty][k];
            a0 += xv * wih5[(j)       * DI_ + k];
            a1 += xv * wih5[(256 + j) * DI_ + k];
            a2 += xv * wih5[(512 + j) * DI_ + k];
            a3 += xv * wih5[(768 + j) * DI_ + k];
        }
    } else {
#pragma unroll 4
        for (int k4 = 0; k4 < 64; k4++) {
            float4 xv = ((const float4*)lx[ty])[k4];
            float4 w0 = wihp[(k4 << 10) + j];
            float4 w1 = wihp[(k4 << 10) + 256 + j];
            float4 w2 = wihp[(k4 << 10) + 512 + j];
            float4 w3 = wihp[(k4 << 10) + 768 + j];
            a0 += xv.x * w0.x + xv.y * w0.y + xv.z * w0.z + xv.w * w0.w;
            a1 += xv.x * w1.x + xv.y * w1.y + xv.z * w1.z + xv.w * w1.w;
            a2 += xv.x * w2.x + xv.y * w2.y + xv.z * w2.z + xv.w * w2.w;
            a3 += xv.x * w3.x + xv.y * w3.y + xv.z * w3.z + xv.w * w3.w;
        }
    }
    if (use_whh) {
#pragma unroll 4
        for (int k4 = 0; k4 < 64; k4++) {
            float4 xv = ((const float4*)lh[ty])[k4];
            float4 w0 = whhp[(k4 << 10) + j];
            float4 w1 = whhp[(k4 << 10) + 256 + j];
            float4 w2 = whhp[(k4 << 10) + 512 + j];
            float4 w3 = whhp[(k4 << 10) + 768 + j];
            a0 += xv.x * w0.x + xv.y * w0.y + xv.z * w0.z + xv.w * w0.w;
            a1 += xv.x * w1.x + xv.y * w1.y + xv.z * w1.z + xv.w * w1.w;
            a2 += xv.x * w2.x + xv.y * w2.y + xv.z * w2.z + xv.w * w2.w;
            a3 += xv.x * w3.x + xv.y * w3.y + xv.z * w3.z + xv.w * w3.w;
        }
    }

    float cold = cprev[(long)b * H_ + j];
    float ii = 1.f / (1.f + expf(-a0));
    float ff = 1.f / (1.f + expf(-a1));
    float gg = tanhf(a2);
    float oo = 1.f / (1.f + expf(-a3));
    float cn = ff * cold + ii * gg;
    float hn = oo * tanhf(cn);
    cout[(long)b * H_ + j] = cn;
    hout[(long)b * H_ + j] = hn;
    if (henc) henc[(long)b * ENCSTRIDE + j] = __float2bfloat16(hn);
}

// ---------------------------------------------------------------------------
// energies[s][b] = dot(h2[b,:], enc[b,s,:])   grid 16384 (b x sblk8) x 256
// ---------------------------------------------------------------------------
__global__ __launch_bounds__(256) void energies_kernel(const float* __restrict__ h2,
                                                       const __hip_bfloat16* __restrict__ enc,
                                                       float* __restrict__ E) {
    __shared__ float lh[H_];
    __shared__ float red[4];
    int b = blockIdx.x >> 6;
    int s0 = (int)(blockIdx.x & 63) * 8;
    int tid = threadIdx.x;
    lh[tid] = h2[b * H_ + tid];
    __syncthreads();
    for (int si = 0; si < 8; si++) {
        int s = s0 + si;
        float p = lh[tid] * __bfloat162float(enc[(long)b * ENCSTRIDE + s * H_ + tid]);
#pragma unroll
        for (int off = 32; off > 0; off >>= 1) p += __shfl_down(p, off);
        if ((tid & 63) == 0) red[tid >> 6] = p;
        __syncthreads();
        if (tid == 0) E[s * B_ + b] = red[0] + red[1] + red[2] + red[3];
        __syncthreads();
    }
}

// ---------------------------------------------------------------------------
// softmax over batch (per s): W[s][b]      grid 512 x 256
// ---------------------------------------------------------------------------
__global__ __launch_bounds__(256) void softmax_kernel(const float* __restrict__ E,
                                                      float* __restrict__ W) {
    __shared__ float red[4];
    int s = blockIdx.x, tid = threadIdx.x;
    float v = E[s * B_ + tid];
    float m = v;
#pragma unroll
    for (int off = 32; off > 0; off >>= 1) m = fmaxf(m, __shfl_down(m, off));
    if ((tid & 63) == 0) red[tid >> 6] = m;
    __syncthreads();
    m = fmaxf(fmaxf(red[0], red[1]), fmaxf(red[2], red[3]));
    __syncthreads();
    float e = expf(v - m);
    float p = e;
#pragma unroll
    for (int off = 32; off > 0; off >>= 1) p += __shfl_down(p, off);
    if ((tid & 63) == 0) red[tid >> 6] = p;
    __syncthreads();
    float sum = red[0] + red[1] + red[2] + red[3];
    W[s * B_ + tid] = e / sum;
}

// ---------------------------------------------------------------------------
// context[b][h] = sum_s W[s][b]*enc[b,s,h]   grid 256 x 256
// writes to d_out (strided by TLEN) and compact ctxc
// ---------------------------------------------------------------------------
__global__ __launch_bounds__(256) void context_kernel(const float* __restrict__ W,
                                                      const __hip_bfloat16* __restrict__ enc,
                                                      float* __restrict__ out_ctx, // +t*H_ pre-offset
                                                      float* __restrict__ ctxc) {
    __shared__ float lw[S_];
    int b = blockIdx.x, tid = threadIdx.x;
    lw[tid] = W[tid * B_ + b];
    lw[256 + tid] = W[(256 + tid) * B_ + b];
    __syncthreads();
    float acc = 0.f;
    const __hip_bfloat16* ep = enc + (long)b * ENCSTRIDE + tid;
#pragma unroll 8
    for (int s = 0; s < S_; s++) acc += lw[s] * __bfloat162float(ep[s * H_]);
    out_ctx[(long)b * (TLEN_ * H_) + tid] = acc;
    ctxc[b * H_ + tid] = acc;
}

// ---------------------------------------------------------------------------
// cats = [h2|ctx]@ww.T + bw; pred = tanh(cats)@wop.T + bop   grid 256 x 64
// ---------------------------------------------------------------------------
__global__ __launch_bounds__(64) void decout_kernel(const float* __restrict__ h2,
                                                    const float* __restrict__ ctx,
                                                    const float* __restrict__ ww,
                                                    const float* __restrict__ bw,
                                                    const float* __restrict__ wop,
                                                    const float* __restrict__ bop,
                                                    float* __restrict__ out0,  // +t*DI_ pre-offset
                                                    float* __restrict__ pred) {
    int b = blockIdx.x, lane = threadIdx.x;
    float a[DI_] = {0.f, 0.f, 0.f, 0.f, 0.f};
    for (int k = lane; k < 2 * H_; k += 64) {
        float v = (k < H_) ? h2[b * H_ + k] : ctx[b * H_ + k - H_];
#pragma unroll
        for (int m = 0; m < DI_; m++) a[m] += v * ww[m * (2 * H_) + k];
    }
#pragma unroll
    for (int m = 0; m < DI_; m++)
        for (int off = 32; off > 0; off >>= 1) a[m] += __shfl_down(a[m], off);
    if (lane == 0) {
        float t5[DI_];
#pragma unroll
        for (int m = 0; m < DI_; m++) t5[m] = tanhf(a[m] + bw[m]);
#pragma unroll
        for (int m2 = 0; m2 < DI_; m2++) {
            float o = bop[m2];
#pragma unroll
            for (int m = 0; m < DI_; m++) o += t5[m] * wop[m2 * DI_ + m];
            out0[(long)b * (TLEN_ * DI_) + m2] = o;
            pred[b * DI_ + m2] = o;
        }
    }
}

// ---------------------------------------------------------------------------
extern "C" void kernel_launch(void* const* d_in, const int* in_sizes, int n_in,
                              void* d_out, int out_size, void* d_ws, size_t ws_size,
                              hipStream_t stream) {
    const float* srcs   = (const float*)d_in[0];
    const float* wih_e1 = (const float*)d_in[1];
    const float* whh_e1 = (const float*)d_in[2];
    const float* b_e1   = (const float*)d_in[3];
    const float* wih_e2 = (const float*)d_in[4];
    const float* whh_e2 = (const float*)d_in[5];
    const float* b_e2   = (const float*)d_in[6];
    const float* wdi    = (const float*)d_in[7];
    const float* bdi    = (const float*)d_in[8];
    const float* wih_d1 = (const float*)d_in[9];
    const float* whh_d1 = (const float*)d_in[10];
    const float* b_d1   = (const float*)d_in[11];
    const float* wih_d2 = (const float*)d_in[12];
    const float* whh_d2 = (const float*)d_in[13];
    const float* b_d2   = (const float*)d_in[14];
    const float* ww     = (const float*)d_in[15];
    const float* bw     = (const float*)d_in[16];
    const float* wop    = (const float*)d_in[17];
    const float* bop    = (const float*)d_in[18];

    float* ws = (float*)d_ws;
    __hip_bfloat16* ENCBF = (__hip_bfloat16*)d_ws;       // 33,554,432 bf16 = 16,777,216 float slots
    size_t o = 16777216;
    float4* PK0 = (float4*)(ws + o); o += 262144;  // whh_e1 packed
    float4* PK1 = (float4*)(ws + o); o += 262144;  // wih_e2 packed
    float4* PK2 = (float4*)(ws + o); o += 262144;  // whh_e2 packed
    float4* PK3 = (float4*)(ws + o); o += 262144;  // whh_d1 packed
    float4* PK4 = (float4*)(ws + o); o += 262144;  // wih_d2 packed
    float* H1A = ws + o; o += 65536;
    float* H1B = ws + o; o += 65536;
    float* H2A = ws + o; o += 65536;
    float* H2B = ws + o; o += 65536;
    float* C1  = ws + o; o += 65536;
    float* C2  = ws + o; o += 65536;
    float* H1D = ws + o; o += 65536;
    float* ZB  = ws + o; o += 65536;
    float* EN  = ws + o; o += 131072;
    float* WSM = ws + o; o += 131072;
    float* CTX = ws + o; o += 65536;
    float* PRD = ws + o; o += 1280;
    float* WEF = ws + o; o += 5120;
    float* BEF = ws + o; o += 1024;

    float* OUT0 = (float*)d_out;
    float* OUT1 = OUT0 + (size_t)B_ * TLEN_ * DI_;   // context_enc base

    dim3 g256(256), t256(256);

    init_kernel<<<g256, t256, 0, stream>>>(H1B, H2B, C1, C2, ZB, PRD);

    pack_kernel<<<g256, t256, 0, stream>>>(whh_e1, PK0);
    pack_kernel<<<g256, t256, 0, stream>>>(wih_e2, PK1);
    pack_kernel<<<g256, t256, 0, stream>>>(whh_e2, PK2);
    pack_kernel<<<g256, t256, 0, stream>>>(whh_d1, PK3);
    pack_kernel<<<g256, t256, 0, stream>>>(wih_d2, PK4);
    weff_kernel<<<dim3(4), t256, 0, stream>>>(wih_d1, wdi, bdi, b_d1, WEF, BEF);

    // ---------------- encoder: 512 steps, two stacked layers ----------------
    for (int t = 0; t < S_; t++) {
        float* h1r = (t & 1) ? H1A : H1B;
        float* h1w = (t & 1) ? H1B : H1A;
        float* h2r = (t & 1) ? H2A : H2B;
        float* h2w = (t & 1) ? H2B : H2A;
        // layer 1: x = srcs[:,t,:] (K=5), h = h1r
        cell_kernel<<<g256, t256, 0, stream>>>(
            srcs + t * DI_, S_ * DI_, wih_e1, nullptr, DI_,
            h1r, PK0, 1, b_e1, C1, C1, h1w, nullptr);
        // layer 2: x = e1[t] = h1w (K=256), h = h2r; write h2w + enc bf16
        cell_kernel<<<g256, t256, 0, stream>>>(
            h1w, H_, nullptr, PK1, H_,
            h2r, PK2, 1, b_e2, C2, C2, h2w, ENCBF + (size_t)t * H_);
    }
    // final states: h_enc = H2B (t=511 odd), c_enc = C2

    // ---------------- decoder: 32 steps ----------------
    for (int t = 0; t < TLEN_; t++) {
        // layer 1: x = pred (K=5 via Weff), h = carry (H2B), c = carry (C2)
        cell_kernel<<<g256, t256, 0, stream>>>(
            PRD, DI_, WEF, nullptr, DI_,
            H2B, PK3, 1, BEF, C2, C1 /*discarded c1*/, H1D, nullptr);
        // layer 2: x = h1d (K=256), h=c=0; writes new carry h->H2B, c->C2
        cell_kernel<<<g256, t256, 0, stream>>>(
            H1D, H_, nullptr, PK4, H_,
            ZB, nullptr, 0, b_d2, ZB, C2, H2B, nullptr);
        energies_kernel<<<dim3(16384), t256, 0, stream>>>(H2B, ENCBF, EN);
        softmax_kernel<<<dim3(512), t256, 0, stream>>>(EN, WSM);
        context_kernel<<<g256, t256, 0, stream>>>(WSM, ENCBF, OUT1 + (size_t)t * H_, CTX);
        decout_kernel<<<g256, dim3(64), 0, stream>>>(H2B, CTX, ww, bw, wop, bop,
                                                     OUT0 + (size_t)t * DI_, PRD);
    }
}

// Round 2
// 16839.082 us; speedup vs baseline: 1.3411x; 1.3411x over previous
//
#include <hip/hip_runtime.h>
#include <hip/hip_bf16.h>

#define B_    256
#define S_    512
#define H_    256
#define TLEN_ 32
#define DI_   5
#define ENCSTRIDE 131072   // S_*H_

// ---------------------------------------------------------------------------
// init: zero state ping-pong buffers, set decoder inp0 = ones
// ---------------------------------------------------------------------------
__global__ __launch_bounds__(256) void init_kernel(float* H1, float* H2, float* C1,
                                                   float* C2, float* ZB, float* PRD) {
    int i = blockIdx.x * 256 + threadIdx.x;      // grid 512 -> 131072
    H1[i] = 0.f; H2[i] = 0.f;
    if (i < 65536) { C1[i] = 0.f; C2[i] = 0.f; ZB[i] = 0.f; }
    if (i < B_ * DI_) PRD[i] = 1.0f;
}

// ---------------------------------------------------------------------------
// pack a [1024][256] row-major weight into [k4][n] float4 layout:
// out[k4*1024 + n] = {w[n][4k4], w[n][4k4+1], w[n][4k4+2], w[n][4k4+3]}
// ---------------------------------------------------------------------------
__global__ __launch_bounds__(256) void pack_kernel(const float* __restrict__ m,
                                                   float4* __restrict__ out) {
    int idx = blockIdx.x * 256 + threadIdx.x;    // grid 256 -> 65536
    int k4 = idx >> 10, n = idx & 1023;
    out[idx] = ((const float4*)m)[n * 64 + k4];
}

// ---------------------------------------------------------------------------
// Weff[n][m] = sum_k wih_d1[n][k]*wdi[k][m]; beff[n] = b_d1[n] + wih_d1[n]·bdi
// ---------------------------------------------------------------------------
__global__ __launch_bounds__(256) void weff_kernel(const float* __restrict__ wih_d1,
                                                   const float* __restrict__ wdi,
                                                   const float* __restrict__ bdi,
                                                   const float* __restrict__ b_d1,
                                                   float* __restrict__ weff,
                                                   float* __restrict__ beff) {
    int n = blockIdx.x * 256 + threadIdx.x;      // grid 4 -> 1024
    float acc[DI_] = {0.f, 0.f, 0.f, 0.f, 0.f};
    float accb = 0.f;
    for (int k = 0; k < H_; k++) {
        float w = wih_d1[n * H_ + k];
        accb += w * bdi[k];
#pragma unroll
        for (int m = 0; m < DI_; m++) acc[m] += w * wdi[k * DI_ + m];
    }
#pragma unroll
    for (int m = 0; m < DI_; m++) weff[n * DI_ + m] = acc[m];
    beff[n] = b_d1[n] + accb;
}

// ---------------------------------------------------------------------------
// dot-chunk helper: a0..a3 += xv · w{0..3}
// ---------------------------------------------------------------------------
__device__ __forceinline__ void dot4(const float4 xv, const float4 w0, const float4 w1,
                                     const float4 w2, const float4 w3,
                                     float& a0, float& a1, float& a2, float& a3) {
    a0 += xv.x * w0.x + xv.y * w0.y + xv.z * w0.z + xv.w * w0.w;
    a1 += xv.x * w1.x + xv.y * w1.y + xv.z * w1.z + xv.w * w1.w;
    a2 += xv.x * w2.x + xv.y * w2.y + xv.z * w2.z + xv.w * w2.w;
    a3 += xv.x * w3.x + xv.y * w3.y + xv.z * w3.z + xv.w * w3.w;
}

__device__ __forceinline__ void lstm_epilogue(float a0, float a1, float a2, float a3,
                                              float cold, float& cn, float& hn) {
    float ii = 1.f / (1.f + expf(-a0));
    float ff = 1.f / (1.f + expf(-a1));
    float gg = tanhf(a2);
    float oo = 1.f / (1.f + expf(-a3));
    cn = ff * cold + ii * gg;
    hn = oo * tanhf(cn);
}

// ---------------------------------------------------------------------------
// Fused encoder step. Launch tau (=t): blocks 0..255 do layer-1 step t
// (if t<512); blocks 256..511 do layer-2 step t-1 (if t>=1). Layer-2 reads
// the h1 slice written by the PREVIOUS launch -> no intra-launch dependency.
// Tile: 16 batch x 16 j, 4 gates per thread. Ping-pong: write slot t&1,
// read slot (t-1)&1.
// ---------------------------------------------------------------------------
__global__ __launch_bounds__(256) void enc_step_kernel(
    int t,
    const float* __restrict__ srcs,
    const float* __restrict__ wih_e1,      // [1024][5] raw
    const float4* __restrict__ whh_e1p,    // packed [64][1024]
    const float4* __restrict__ wih_e2p,
    const float4* __restrict__ whh_e2p,
    const float* __restrict__ b_e1,
    const float* __restrict__ b_e2,
    float* __restrict__ H1,                // [2][65536] ping-pong
    float* __restrict__ H2,                // [2][65536] ping-pong
    float* __restrict__ C1,
    float* __restrict__ C2,
    __hip_bfloat16* __restrict__ encbf)    // [b][s][h]
{
    __shared__ float sA[16][260];
    __shared__ float sB[16][260];
    int tid = threadIdx.x;

    if (blockIdx.x < 256) {
        // -------- layer 1, step t --------
        if (t >= S_) return;
        int bid = blockIdx.x;
        int b0 = (bid >> 4) * 16, j0 = (bid & 15) * 16;
        if (tid < 16 * DI_) {
            int r = tid / DI_, c = tid % DI_;
            sA[r][c] = srcs[((long)(b0 + r) * S_ + t) * DI_ + c];
        }
        const float* hp = H1 + (((t & 1) ^ 1) << 16);
        for (int i = tid; i < 1024; i += 256) {
            int r = i >> 6, c4 = i & 63;
            ((float4*)&sB[r][0])[c4] = ((const float4*)(hp + (b0 + r) * H_))[c4];
        }
        __syncthreads();
        int bl = tid >> 4, jl = tid & 15, b = b0 + bl, j = j0 + jl;
        float a0 = b_e1[j], a1 = b_e1[256 + j], a2 = b_e1[512 + j], a3 = b_e1[768 + j];
#pragma unroll
        for (int k = 0; k < DI_; k++) {
            float xv = sA[bl][k];
            a0 += xv * wih_e1[j * DI_ + k];
            a1 += xv * wih_e1[(256 + j) * DI_ + k];
            a2 += xv * wih_e1[(512 + j) * DI_ + k];
            a3 += xv * wih_e1[(768 + j) * DI_ + k];
        }
#pragma unroll 4
        for (int k4 = 0; k4 < 64; k4++) {
            float4 xv = ((const float4*)&sB[bl][0])[k4];
            dot4(xv, whh_e1p[(k4 << 10) + j], whh_e1p[(k4 << 10) + 256 + j],
                 whh_e1p[(k4 << 10) + 512 + j], whh_e1p[(k4 << 10) + 768 + j],
                 a0, a1, a2, a3);
        }
        int idx = b * H_ + j;
        float cn, hn;
        lstm_epilogue(a0, a1, a2, a3, C1[idx], cn, hn);
        C1[idx] = cn;
        H1[((t & 1) << 16) + idx] = hn;
    } else {
        // -------- layer 2, step u = t-1 --------
        if (t < 1) return;
        int u = t - 1;
        int bid = blockIdx.x - 256;
        int b0 = (bid >> 4) * 16, j0 = (bid & 15) * 16;
        const float* xp = H1 + ((u & 1) << 16);          // e1[u] (written last launch)
        const float* hp = H2 + (((u & 1) ^ 1) << 16);    // h2[u-1]
        for (int i = tid; i < 1024; i += 256) {
            int r = i >> 6, c4 = i & 63;
            ((float4*)&sA[r][0])[c4] = ((const float4*)(xp + (b0 + r) * H_))[c4];
            ((float4*)&sB[r][0])[c4] = ((const float4*)(hp + (b0 + r) * H_))[c4];
        }
        __syncthreads();
        int bl = tid >> 4, jl = tid & 15, b = b0 + bl, j = j0 + jl;
        float a0 = b_e2[j], a1 = b_e2[256 + j], a2 = b_e2[512 + j], a3 = b_e2[768 + j];
#pragma unroll 4
        for (int k4 = 0; k4 < 64; k4++) {
            float4 xv = ((const float4*)&sA[bl][0])[k4];
            dot4(xv, wih_e2p[(k4 << 10) + j], wih_e2p[(k4 << 10) + 256 + j],
                 wih_e2p[(k4 << 10) + 512 + j], wih_e2p[(k4 << 10) + 768 + j],
                 a0, a1, a2, a3);
        }
#pragma unroll 4
        for (int k4 = 0; k4 < 64; k4++) {
            float4 xv = ((const float4*)&sB[bl][0])[k4];
            dot4(xv, whh_e2p[(k4 << 10) + j], whh_e2p[(k4 << 10) + 256 + j],
                 whh_e2p[(k4 << 10) + 512 + j], whh_e2p[(k4 << 10) + 768 + j],
                 a0, a1, a2, a3);
        }
        int idx = b * H_ + j;
        float cn, hn;
        lstm_epilogue(a0, a1, a2, a3, C2[idx], cn, hn);
        C2[idx] = cn;
        H2[((u & 1) << 16) + idx] = hn;
        encbf[(long)b * ENCSTRIDE + u * H_ + j] = __float2bfloat16(hn);
    }
}

// ---------------------------------------------------------------------------
// Decoder LSTM cell, 16x16 tile, grid 256 x 256.
// kx==5: raw w5 [1024][5]; kx==256: packed wxp. use_whh: add hprev @ whh.
// ---------------------------------------------------------------------------
__global__ __launch_bounds__(256) void dec_cell_kernel(
    const float* __restrict__ x, int xstride,
    const float* __restrict__ w5,
    const float4* __restrict__ wxp, int kx,
    const float* __restrict__ hprev,
    const float4* __restrict__ whhp, int use_whh,
    const float* __restrict__ bias,
    const float* __restrict__ cprev,
    float* __restrict__ cout,
    float* __restrict__ hout)
{
    __shared__ float sA[16][260];
    __shared__ float sB[16][260];
    int tid = threadIdx.x;
    int b0 = ((int)blockIdx.x >> 4) * 16, j0 = ((int)blockIdx.x & 15) * 16;

    if (kx == DI_) {
        if (tid < 16 * DI_) {
            int r = tid / DI_, c = tid % DI_;
            sA[r][c] = x[(b0 + r) * xstride + c];
        }
    } else {
        for (int i = tid; i < 1024; i += 256) {
            int r = i >> 6, c4 = i & 63;
            ((float4*)&sA[r][0])[c4] = ((const float4*)(x + (long)(b0 + r) * xstride))[c4];
        }
    }
    if (use_whh) {
        for (int i = tid; i < 1024; i += 256) {
            int r = i >> 6, c4 = i & 63;
            ((float4*)&sB[r][0])[c4] = ((const float4*)(hprev + (long)(b0 + r) * H_))[c4];
        }
    }
    __syncthreads();

    int bl = tid >> 4, jl = tid & 15, b = b0 + bl, j = j0 + jl;
    float a0 = bias[j], a1 = bias[256 + j], a2 = bias[512 + j], a3 = bias[768 + j];

    if (kx == DI_) {
#pragma unroll
        for (int k = 0; k < DI_; k++) {
            float xv = sA[bl][k];
            a0 += xv * w5[j * DI_ + k];
            a1 += xv * w5[(256 + j) * DI_ + k];
            a2 += xv * w5[(512 + j) * DI_ + k];
            a3 += xv * w5[(768 + j) * DI_ + k];
        }
    } else {
#pragma unroll 4
        for (int k4 = 0; k4 < 64; k4++) {
            float4 xv = ((const float4*)&sA[bl][0])[k4];
            dot4(xv, wxp[(k4 << 10) + j], wxp[(k4 << 10) + 256 + j],
                 wxp[(k4 << 10) + 512 + j], wxp[(k4 << 10) + 768 + j], a0, a1, a2, a3);
        }
    }
    if (use_whh) {
#pragma unroll 4
        for (int k4 = 0; k4 < 64; k4++) {
            float4 xv = ((const float4*)&sB[bl][0])[k4];
            dot4(xv, whhp[(k4 << 10) + j], whhp[(k4 << 10) + 256 + j],
                 whhp[(k4 << 10) + 512 + j], whhp[(k4 << 10) + 768 + j], a0, a1, a2, a3);
        }
    }
    int idx = b * H_ + j;
    float cn, hn;
    lstm_epilogue(a0, a1, a2, a3, cprev[idx], cn, hn);
    cout[idx] = cn;
    hout[idx] = hn;
}

// ---------------------------------------------------------------------------
// energies[s][b] = dot(h2[b,:], enc[b,s,:])   grid 16384 (b x sblk8) x 256
// ---------------------------------------------------------------------------
__global__ __launch_bounds__(256) void energies_kernel(const float* __restrict__ h2,
                                                       const __hip_bfloat16* __restrict__ enc,
                                                       float* __restrict__ E) {
    __shared__ float lh[H_];
    __shared__ float red[4];
    int b = blockIdx.x >> 6;
    int s0 = (int)(blockIdx.x & 63) * 8;
    int tid = threadIdx.x;
    lh[tid] = h2[b * H_ + tid];
    __syncthreads();
    for (int si = 0; si < 8; si++) {
        int s = s0 + si;
        float p = lh[tid] * __bfloat162float(enc[(long)b * ENCSTRIDE + s * H_ + tid]);
#pragma unroll
        for (int off = 32; off > 0; off >>= 1) p += __shfl_down(p, off);
        if ((tid & 63) == 0) red[tid >> 6] = p;
        __syncthreads();
        if (tid == 0) E[s * B_ + b] = red[0] + red[1] + red[2] + red[3];
        __syncthreads();
    }
}

// ---------------------------------------------------------------------------
// softmax over batch (per s): W[s][b]      grid 512 x 256
// ---------------------------------------------------------------------------
__global__ __launch_bounds__(256) void softmax_kernel(const float* __restrict__ E,
                                                      float* __restrict__ W) {
    __shared__ float red[4];
    int s = blockIdx.x, tid = threadIdx.x;
    float v = E[s * B_ + tid];
    float m = v;
#pragma unroll
    for (int off = 32; off > 0; off >>= 1) m = fmaxf(m, __shfl_down(m, off));
    if ((tid & 63) == 0) red[tid >> 6] = m;
    __syncthreads();
    m = fmaxf(fmaxf(red[0], red[1]), fmaxf(red[2], red[3]));
    __syncthreads();
    float e = expf(v - m);
    float p = e;
#pragma unroll
    for (int off = 32; off > 0; off >>= 1) p += __shfl_down(p, off);
    if ((tid & 63) == 0) red[tid >> 6] = p;
    __syncthreads();
    float sum = red[0] + red[1] + red[2] + red[3];
    W[s * B_ + tid] = e / sum;
}

// ---------------------------------------------------------------------------
// context[b][h] = sum_s W[s][b]*enc[b,s,h]   grid 256 x 256
// ---------------------------------------------------------------------------
__global__ __launch_bounds__(256) void context_kernel(const float* __restrict__ W,
                                                      const __hip_bfloat16* __restrict__ enc,
                                                      float* __restrict__ out_ctx, // +t*H_ pre-offset
                                                      float* __restrict__ ctxc) {
    __shared__ float lw[S_];
    int b = blockIdx.x, tid = threadIdx.x;
    lw[tid] = W[tid * B_ + b];
    lw[256 + tid] = W[(256 + tid) * B_ + b];
    __syncthreads();
    float acc = 0.f;
    const __hip_bfloat16* ep = enc + (long)b * ENCSTRIDE + tid;
#pragma unroll 8
    for (int s = 0; s < S_; s++) acc += lw[s] * __bfloat162float(ep[s * H_]);
    out_ctx[(long)b * (TLEN_ * H_) + tid] = acc;
    ctxc[b * H_ + tid] = acc;
}

// ---------------------------------------------------------------------------
// cats = [h2|ctx]@ww.T + bw; pred = tanh(cats)@wop.T + bop   grid 256 x 64
// ---------------------------------------------------------------------------
__global__ __launch_bounds__(64) void decout_kernel(const float* __restrict__ h2,
                                                    const float* __restrict__ ctx,
                                                    const float* __restrict__ ww,
                                                    const float* __restrict__ bw,
                                                    const float* __restrict__ wop,
                                                    const float* __restrict__ bop,
                                                    float* __restrict__ out0,  // +t*DI_ pre-offset
                                                    float* __restrict__ pred) {
    int b = blockIdx.x, lane = threadIdx.x;
    float a[DI_] = {0.f, 0.f, 0.f, 0.f, 0.f};
    for (int k = lane; k < 2 * H_; k += 64) {
        float v = (k < H_) ? h2[b * H_ + k] : ctx[b * H_ + k - H_];
#pragma unroll
        for (int m = 0; m < DI_; m++) a[m] += v * ww[m * (2 * H_) + k];
    }
#pragma unroll
    for (int m = 0; m < DI_; m++)
        for (int off = 32; off > 0; off >>= 1) a[m] += __shfl_down(a[m], off);
    if (lane == 0) {
        float t5[DI_];
#pragma unroll
        for (int m = 0; m < DI_; m++) t5[m] = tanhf(a[m] + bw[m]);
#pragma unroll
        for (int m2 = 0; m2 < DI_; m2++) {
            float o = bop[m2];
#pragma unroll
            for (int m = 0; m < DI_; m++) o += t5[m] * wop[m2 * DI_ + m];
            out0[(long)b * (TLEN_ * DI_) + m2] = o;
            pred[b * DI_ + m2] = o;
        }
    }
}

// ---------------------------------------------------------------------------
extern "C" void kernel_launch(void* const* d_in, const int* in_sizes, int n_in,
                              void* d_out, int out_size, void* d_ws, size_t ws_size,
                              hipStream_t stream) {
    const float* srcs   = (const float*)d_in[0];
    const float* wih_e1 = (const float*)d_in[1];
    const float* whh_e1 = (const float*)d_in[2];
    const float* b_e1   = (const float*)d_in[3];
    const float* wih_e2 = (const float*)d_in[4];
    const float* whh_e2 = (const float*)d_in[5];
    const float* b_e2   = (const float*)d_in[6];
    const float* wdi    = (const float*)d_in[7];
    const float* bdi    = (const float*)d_in[8];
    const float* wih_d1 = (const float*)d_in[9];
    const float* whh_d1 = (const float*)d_in[10];
    const float* b_d1   = (const float*)d_in[11];
    const float* wih_d2 = (const float*)d_in[12];
    const float* whh_d2 = (const float*)d_in[13];
    const float* b_d2   = (const float*)d_in[14];
    const float* ww     = (const float*)d_in[15];
    const float* bw     = (const float*)d_in[16];
    const float* wop    = (const float*)d_in[17];
    const float* bop    = (const float*)d_in[18];

    float* ws = (float*)d_ws;
    __hip_bfloat16* ENCBF = (__hip_bfloat16*)d_ws;   // 33.5M bf16 = 16,777,216 float slots
    size_t o = 16777216;
    float4* PKE1 = (float4*)(ws + o); o += 262144;   // whh_e1 packed
    float4* PKX2 = (float4*)(ws + o); o += 262144;   // wih_e2 packed
    float4* PKH2 = (float4*)(ws + o); o += 262144;   // whh_e2 packed
    float4* PKD1 = (float4*)(ws + o); o += 262144;   // whh_d1 packed
    float4* PKD2 = (float4*)(ws + o); o += 262144;   // wih_d2 packed
    float* H1  = ws + o; o += 131072;                // [2][65536] ping-pong
    float* H2  = ws + o; o += 131072;                // [2][65536] ping-pong
    float* C1  = ws + o; o += 65536;
    float* C2  = ws + o; o += 65536;
    float* ZB  = ws + o; o += 65536;
    float* H1D = ws + o; o += 65536;
    float* C1D = ws + o; o += 65536;
    float* EN  = ws + o; o += 131072;
    float* WSM = ws + o; o += 131072;
    float* CTX = ws + o; o += 65536;
    float* PRD = ws + o; o += 1280;
    float* WEF = ws + o; o += 5120;
    float* BEF = ws + o; o += 1024;

    float* OUT0 = (float*)d_out;
    float* OUT1 = OUT0 + (size_t)B_ * TLEN_ * DI_;   // context_enc base

    dim3 t256(256);

    init_kernel<<<dim3(512), t256, 0, stream>>>(H1, H2, C1, C2, ZB, PRD);

    pack_kernel<<<dim3(256), t256, 0, stream>>>(whh_e1, PKE1);
    pack_kernel<<<dim3(256), t256, 0, stream>>>(wih_e2, PKX2);
    pack_kernel<<<dim3(256), t256, 0, stream>>>(whh_e2, PKH2);
    pack_kernel<<<dim3(256), t256, 0, stream>>>(whh_d1, PKD1);
    pack_kernel<<<dim3(256), t256, 0, stream>>>(wih_d2, PKD2);
    weff_kernel<<<dim3(4), t256, 0, stream>>>(wih_d1, wdi, bdi, b_d1, WEF, BEF);

    // ---------------- encoder: 513 pipelined fused launches ----------------
    for (int t = 0; t <= S_; t++) {
        enc_step_kernel<<<dim3(512), t256, 0, stream>>>(
            t, srcs, wih_e1, PKE1, PKX2, PKH2, b_e1, b_e2,
            H1, H2, C1, C2, ENCBF);
    }
    // final states: h_enc = H2 slot (511&1)=1, c_enc = C2
    float* H2F = H2 + 65536;

    // ---------------- decoder: 32 steps ----------------
    for (int t = 0; t < TLEN_; t++) {
        // layer 1: x = pred (K=5 via Weff), h = carry h2, c = carry c2
        dec_cell_kernel<<<dim3(256), t256, 0, stream>>>(
            PRD, DI_, WEF, nullptr, DI_,
            H2F, PKD1, 1, BEF, C2, C1D, H1D);
        // layer 2: x = h1d (K=256), h=c=0; writes new carry (h2 -> H2F, c2 -> C2)
        dec_cell_kernel<<<dim3(256), t256, 0, stream>>>(
            H1D, H_, nullptr, PKD2, H_,
            ZB, nullptr, 0, b_d2, ZB, C2, H2F);
        energies_kernel<<<dim3(16384), t256, 0, stream>>>(H2F, ENCBF, EN);
        softmax_kernel<<<dim3(512), t256, 0, stream>>>(EN, WSM);
        context_kernel<<<dim3(256), t256, 0, stream>>>(WSM, ENCBF, OUT1 + (size_t)t * H_, CTX);
        decout_kernel<<<dim3(256), dim3(64), 0, stream>>>(H2F, CTX, ww, bw, wop, bop,
                                                          OUT0 + (size_t)t * DI_, PRD);
    }
}